// Round 2
// baseline (670.950 us; speedup 1.0000x reference)
//
#include <hip/hip_runtime.h>
#include <stdint.h>

typedef unsigned short ushort_t;

__device__ __forceinline__ float bf2f(unsigned short u) {
  union { unsigned int i; float f; } c; c.i = ((unsigned int)u) << 16; return c.f;
}
__device__ __forceinline__ unsigned short f2bf(float f) {
  union { float f; unsigned int i; } c; c.f = f;
  unsigned int r = c.i + 0x7FFFu + ((c.i >> 16) & 1u);
  return (unsigned short)(r >> 16);
}
// NaN-propagating relu (tripwire: NaN stays visible)
__device__ __forceinline__ float relu_nanprop(float v) { return (v < 0.f) ? 0.f : v; }

// async global->LDS 16B copy: LDS dest = wave-uniform base + lane*16 (HW-implicit)
__device__ __forceinline__ void async_copy16(const void* g, void* l) {
  __builtin_amdgcn_global_load_lds(
      (const __attribute__((address_space(1))) unsigned int*)(uintptr_t)g,
      (__attribute__((address_space(3))) unsigned int*)(uintptr_t)l,
      16, 0, 0);
}

typedef __attribute__((ext_vector_type(8))) short s16x8;
typedef __attribute__((ext_vector_type(4))) float f32x4;

__device__ __forceinline__ int edge_at(const void* edges, int wide, int idx) {
  if (wide) return (int)((const long long*)edges)[idx];
  return ((const int*)edges)[idx];
}

// ---------------- setup: zero scratch + dtype detects (1 launch) ----------------
// zero region: deg(N) fill(N) degS(N) fillS(N) sums(1024)
__global__ void setup_kernel(int* __restrict__ zreg2, int N,
                             const int* __restrict__ e32, int n32, int* __restrict__ eflag,
                             const unsigned int* __restrict__ x, int nw, int* __restrict__ fF) {
  int b = blockIdx.x, tid = threadIdx.x;
  if (b < 256) {
    int total = 4 * N + 1024;
    for (int i = b * 256 + tid; i < total; i += 256 * 256) zreg2[i] = 0;
  } else if (b == 256) {
    __shared__ int any;
    if (tid == 0) any = 0;
    __syncthreads();
    for (int i = tid; i < 4096; i += 256) {
      int idx = 2 * i + 1;
      if (idx < n32 && e32[idx] != 0) any = 1;
    }
    __syncthreads();
    if (tid == 0) eflag[0] = (any == 0) ? 1 : 0;  // 1 => int64
  } else {
    __shared__ int cnt;
    if (tid == 0) cnt = 0;
    __syncthreads();
    int local = 0;
    for (int i = tid; i < 4096 && i < nw; i += 256) {
      unsigned int low = x[i] & 0xFFFFu;
      unsigned int e = (low >> 7) & 0xFFu;
      if (low != 0u && (e < 96u || e > 144u)) local++;
    }
    atomicAdd(&cnt, local);
    __syncthreads();
    if (tid == 0) fF[0] = (cnt > 1024) ? 1 : 0;  // 1 => float32 inputs
  }
}

// ---------------- cvt_all: x0 cvt + params + 2x weight transpose + hist (1 launch) ----
// R15: hist block now builds BOTH dst-degree (deg) and src-degree (degS).
__global__ void cvt_all_kernel(const void* __restrict__ x0, ushort_t* __restrict__ x0b, int nx,
                               const void* p0, const void* p1, const void* p2,
                               const void* p3, const void* p4, const void* p5,
                               ushort_t* o0, ushort_t* o1, ushort_t* o2,
                               ushort_t* o3, ushort_t* o4, ushort_t* o5,
                               const void* W10, const void* W11, const void* W12, const void* W13,
                               ushort_t* __restrict__ wcat1,
                               const void* W20, const void* W21, const void* W22, const void* W23,
                               ushort_t* __restrict__ wcat2,
                               const void* __restrict__ edges, int* __restrict__ deg,
                               int* __restrict__ degS,
                               int E, int Nn,
                               const int* __restrict__ eflag, const int* __restrict__ fF) {
  int b = blockIdx.x, tid = threadIdx.x;
  int f = fF[0];
  if (b < 4096) {
    for (int i = b * 256 + tid; i < nx; i += 4096 * 256)
      x0b[i] = f ? f2bf(((const float*)x0)[i]) : ((const ushort_t*)x0)[i];
  } else if (b == 4096) {
    const void* ins[6] = {p0, p1, p2, p3, p4, p5};
    ushort_t* outs[6] = {o0, o1, o2, o3, o4, o5};
    const int segs[7] = {0, 256, 512, 768, 896, 1024, 1152};
    for (int i = tid; i < 1152; i += 256) {
      int s = 0;
      while (i >= segs[s + 1]) s++;
      int li = i - segs[s];
      outs[s][li] = f ? f2bf(((const float*)ins[s])[li]) : ((const ushort_t*)ins[s])[li];
    }
  } else if (b < 4609) {  // layer-1 weights: K=128, C=256 x4 -> wcat1[1024][128]
    const void* Ws[4] = {W10, W11, W12, W13};
    int per = 128 * 256, total = 4 * per;
    for (int i = (b - 4097) * 256 + tid; i < total; i += 512 * 256) {
      int wsel = i / per, rem = i - wsel * per;
      int k = rem >> 8, c = rem & 255;
      ushort_t v = f ? f2bf(((const float*)Ws[wsel])[rem]) : ((const ushort_t*)Ws[wsel])[rem];
      wcat1[(size_t)(wsel * 256 + c) * 128 + k] = v;
    }
  } else if (b < 5121) {  // layer-2 weights: K=256, C=256,256,128,128 -> wcat2[768][256]
    int per01 = 256 * 256, per23 = 256 * 128;
    int total = 2 * per01 + 2 * per23;
    for (int i = (b - 4609) * 256 + tid; i < total; i += 512 * 256) {
      const void* W; int rem, C, rowoff;
      if (i < per01)                 { W = W20; rem = i;                  C = 256; rowoff = 0; }
      else if (i < 2 * per01)        { W = W21; rem = i - per01;          C = 256; rowoff = 256; }
      else if (i < 2 * per01 + per23){ W = W22; rem = i - 2 * per01;      C = 128; rowoff = 512; }
      else                           { W = W23; rem = i - 2 * per01 - per23; C = 128; rowoff = 640; }
      int k = rem / C, c = rem - k * C;
      ushort_t v = f ? f2bf(((const float*)W)[rem]) : ((const ushort_t*)W)[rem];
      wcat2[(size_t)(rowoff + c) * 256 + k] = v;
    }
  } else {  // hist: 1024 blocks, both endpoints
    int wide = eflag[0];
    for (int e = (b - 5121) * 256 + tid; e < E; e += 1024 * 256) {
      int s = edge_at(edges, wide, e);
      int d = edge_at(edges, wide, E + e);
      if (d < 0) d = 0; if (d >= Nn) d = Nn - 1;
      if (s < 0) s = 0; if (s >= Nn) s = Nn - 1;
      atomicAdd(&deg[d], 1);
      atomicAdd(&degS[s], 1);
    }
  }
}

// 3-phase parallel scan (chunk = 256): supports N <= 65536
// [R13 post-mortem: single-kernel scan with per-block redundant prefix is a serial
// dependent-load chain (~195 iters in the last block) => ~+20us. Keep 3-phase.]
__global__ void chunk_sum_kernel(const int* __restrict__ deg, int* __restrict__ csum, int n) {
  int b = blockIdx.x, t = threadIdx.x, i = b * 256 + t;
  int v = (i < n) ? deg[i] : 0;
  __shared__ int ws[4];
#pragma unroll
  for (int o = 32; o > 0; o >>= 1) v += __shfl_down(v, o);
  if ((t & 63) == 0) ws[t >> 6] = v;
  __syncthreads();
  if (t == 0) csum[b] = ws[0] + ws[1] + ws[2] + ws[3];
}

__global__ void scan_small_kernel(const int* __restrict__ csum, int* __restrict__ cpre,
                                  int nc, int* __restrict__ offs, int N) {
  __shared__ int tmp[256];
  int t = threadIdx.x;
  int v = (t < nc) ? csum[t] : 0;
  tmp[t] = v;
  __syncthreads();
  for (int off = 1; off < 256; off <<= 1) {
    int x = (t >= off) ? tmp[t - off] : 0;
    __syncthreads();
    tmp[t] += x;
    __syncthreads();
  }
  if (t < nc) cpre[t] = tmp[t] - v;
  if (t == 255) offs[N] = tmp[255];
}

__global__ void scan_final_kernel(const int* __restrict__ deg, const int* __restrict__ cpre,
                                  int* __restrict__ offs, int n) {
  int b = blockIdx.x, t = threadIdx.x, i = b * 256 + t;
  __shared__ int tmp[256];
  int v = (i < n) ? deg[i] : 0;
  tmp[t] = v;
  __syncthreads();
  for (int off = 1; off < 256; off <<= 1) {
    int x = (t >= off) ? tmp[t - off] : 0;
    __syncthreads();
    tmp[t] += x;
    __syncthreads();
  }
  if (i < n) offs[i] = cpre[b] + tmp[t] - v;
}

// R15 pass A: bucket edges into EXACTLY src-sorted (esrc, edst) arrays.
__global__ void scatterS_kernel(const void* __restrict__ edges, const int* __restrict__ flag,
                                const int* __restrict__ offsS, int* __restrict__ fillS,
                                int* __restrict__ esrc, int* __restrict__ edst, int E, int Nn) {
  int wide = flag[0];
  for (int e = blockIdx.x * blockDim.x + threadIdx.x; e < E; e += gridDim.x * blockDim.x) {
    int s = edge_at(edges, wide, e);
    int d = edge_at(edges, wide, E + e);
    if (d < 0) d = 0; if (d >= Nn) d = Nn - 1;
    if (s < 0) s = 0; if (s >= Nn) s = Nn - 1;
    int p = offsS[s] + atomicAdd(&fillS[s], 1);
    if (p < 0) p = 0; if (p >= E) p = E - 1;
    esrc[p] = s;
    edst[p] = d;
  }
}

// R15 pass B: fill dst-CSR from the src-sorted stream => per-dst lists come out
// approximately src-ascending (atomic arrival ~ stream order). Concurrent attn
// waves at similar loop depth then hit the same src window -> L3-resident K/V.
__global__ void scatter2_kernel(const int* __restrict__ esrc, const int* __restrict__ edst,
                                const int* __restrict__ offs, int* __restrict__ fill,
                                int* __restrict__ srcS, int E) {
  for (int e = blockIdx.x * blockDim.x + threadIdx.x; e < E; e += gridDim.x * blockDim.x) {
    int s = esrc[e], d = edst[e];
    int p = offs[d] + atomicAdd(&fill[d], 1);
    if (p < 0) p = 0; if (p >= E) p = E - 1;
    srcS[p] = s;
  }
}

// ---------------- fused 4-way GEMM: [q|k|v|h] = A @ Wcat, bf16 in/out ----------------
// R11 config (best measured): 128x128 tile, acc 4x4, global_load_lds staging, grid
// x=M-tile / y=col-tile, hoisted-section SCALAR epilogue (fire-and-forget stores).
// [R12: LDS-coalesced epilogue (+34KB LDS, +barrier) and x=col grid swap regressed;
//  stores with no dependent consumer were already cheap.]
// [R8: 128x256 tile = 1 wave/SIMD = 10% occ = 204 us. Occupancy >> A-reuse here.]
__global__ __launch_bounds__(256)
void gemm4_kernel(const ushort_t* __restrict__ A, const ushort_t* __restrict__ BT,
                  ushort_t* __restrict__ o0, ushort_t* __restrict__ o1,
                  ushort_t* __restrict__ o2, ushort_t* __restrict__ o3,
                  const ushort_t* __restrict__ bias3,
                  int M, int K, int NC, int b0, int b1, int b2) {
  __shared__ __align__(16) ushort_t As[128 * 32];
  __shared__ __align__(16) ushort_t Bs[128 * 32];
  int tid = threadIdx.x;
  int lane = tid & 63, wave = tid >> 6;
  int tm = blockIdx.x * 128, tn = blockIdx.y * 128;
  int wm = (wave >> 1) * 64, wn = (wave & 1) * 64;
  int q = lane >> 4, l = lane & 15;
  f32x4 acc[4][4];
#pragma unroll
  for (int a = 0; a < 4; a++)
#pragma unroll
    for (int b = 0; b < 4; b++) acc[a][b] = (f32x4){0.f, 0.f, 0.f, 0.f};

  int lrow = lane >> 2, c8 = (lane & 3) * 8;
  for (int k0 = 0; k0 < K; k0 += 32) {
#pragma unroll
    for (int t = 0; t < 2; t++) {
      int chunk = t * 4 + wave;           // 0..7, 16 rows each
      int row = chunk * 16 + lrow;
      int ra = tm + row; if (ra > M - 1) ra = M - 1;
      async_copy16(&A[(size_t)ra * K + k0 + c8], &As[chunk * 512]);
      async_copy16(&BT[(size_t)(tn + row) * K + k0 + c8], &Bs[chunk * 512]);
    }
    __syncthreads();
    s16x8 af[4], bfr[4];
#pragma unroll
    for (int mf = 0; mf < 4; mf++) af[mf] = *(const s16x8*)&As[(wm + mf * 16 + l) * 32 + q * 8];
#pragma unroll
    for (int nf = 0; nf < 4; nf++) bfr[nf] = *(const s16x8*)&Bs[(wn + nf * 16 + l) * 32 + q * 8];
#pragma unroll
    for (int mf = 0; mf < 4; mf++)
#pragma unroll
      for (int nf = 0; nf < 4; nf++)
        acc[mf][nf] = __builtin_amdgcn_mfma_f32_16x16x32_bf16(af[mf], bfr[nf], acc[mf][nf], 0, 0, 0);
    __syncthreads();
  }
  // Hoisted section select (tile is 128-aligned; sections are 128-multiples).
  ushort_t* op; int sbase, w; bool addb = false;
  if (tn < b0)      { op = o0; sbase = 0;  w = b0; }
  else if (tn < b1) { op = o1; sbase = b0; w = b1 - b0; }
  else if (tn < b2) { op = o2; sbase = b1; w = b2 - b1; }
  else              { op = o3; sbase = b2; w = NC - b2; addb = true; }
  int lc0 = tn + wn - sbase + l;
  float bv[4];
#pragma unroll
  for (int nf = 0; nf < 4; nf++) bv[nf] = addb ? bf2f(bias3[lc0 + nf * 16]) : 0.f;
  // C/D layout: col = lane&15, row = (lane>>4)*4 + reg   [m89-verified]
#pragma unroll
  for (int mf = 0; mf < 4; mf++) {
#pragma unroll
    for (int j = 0; j < 4; j++) {
      int r = tm + wm + mf * 16 + q * 4 + j;
      if (r < M) {
#pragma unroll
        for (int nf = 0; nf < 4; nf++)
          op[(size_t)r * w + lc0 + nf * 16] = f2bf(acc[mf][nf][j] + bv[nf]);
      }
    }
  }
}

// ---------------- fused attention + aggregation, one WAVE per dst node ----------------
// R14: 16-lane-per-edge groups (4 edges/wave-iter). Each lane owns 16 dims (32B).
// [R14 post-mortem: VALUBusy 54->36 as predicted but dur flat => gather-latency/
//  HBM-refetch-bound, not issue-bound. R15 attacks FETCH_SIZE via src-sorted lists;
//  this kernel is UNCHANGED.]
__global__ __launch_bounds__(256)
void attn_kernel(const ushort_t* __restrict__ q, const ushort_t* __restrict__ k,
                 const ushort_t* __restrict__ v, const int* __restrict__ offs,
                 const int* __restrict__ srcS, ushort_t* __restrict__ h, int dout, int Nn) {
  int lane = threadIdx.x & 63, wave = threadIdx.x >> 6;
  int n = blockIdx.x * 4 + wave;
  if (n >= Nn) return;
  int g = lane >> 4, sub = lane & 15;

  // q: 16 dims per lane (all 4 groups hold the same dims for their own edge)
  s16x8 q0 = __builtin_nontemporal_load((const s16x8*)(q + (size_t)n * 256 + sub * 16));
  s16x8 q1 = __builtin_nontemporal_load((const s16x8*)(q + (size_t)n * 256 + sub * 16 + 8));
  float qf[16];
#pragma unroll
  for (int i = 0; i < 8; i++) {
    qf[i]     = bf2f((unsigned short)q0[i]);
    qf[8 + i] = bf2f((unsigned short)q1[i]);
  }

  int e0 = offs[n], e1 = offs[n + 1];
  float wsum = 0.f;

  if (dout == 256) {
    float acc[16];
#pragma unroll
    for (int i = 0; i < 16; i++) acc[i] = 0.f;
    int j = e0;
    for (; j + 4 <= e1; j += 4) {
      int s = __builtin_nontemporal_load(srcS + j + g);
      if (s < 0 || s >= Nn) s = 0;
      const ushort_t* kp = k + (size_t)s * 256 + sub * 16;
      const ushort_t* vp = v + (size_t)s * 256 + sub * 16;
      s16x8 k0 = *(const s16x8*)kp, k1 = *(const s16x8*)(kp + 8);
      s16x8 v0 = *(const s16x8*)vp, v1 = *(const s16x8*)(vp + 8);
      float pa = 0.f, pb = 0.f;
#pragma unroll
      for (int i = 0; i < 8; i++) {
        pa += qf[i] * bf2f((unsigned short)k0[i]);
        pb += qf[8 + i] * bf2f((unsigned short)k1[i]);
      }
      float p = pa + pb;
      p += __shfl_xor(p, 1); p += __shfl_xor(p, 2);
      p += __shfl_xor(p, 4); p += __shfl_xor(p, 8);
      float w = __expf(p * 0.0625f);
      wsum += w;
#pragma unroll
      for (int i = 0; i < 8; i++) {
        acc[i]     += w * bf2f((unsigned short)v0[i]);
        acc[8 + i] += w * bf2f((unsigned short)v1[i]);
      }
    }
    int rem = e1 - j;
    if (rem > 0) {
      bool valid = g < rem;
      int s = __builtin_nontemporal_load(srcS + (valid ? (j + g) : j));
      if (s < 0 || s >= Nn) s = 0;
      const ushort_t* kp = k + (size_t)s * 256 + sub * 16;
      const ushort_t* vp = v + (size_t)s * 256 + sub * 16;
      s16x8 k0 = *(const s16x8*)kp, k1 = *(const s16x8*)(kp + 8);
      s16x8 v0 = *(const s16x8*)vp, v1 = *(const s16x8*)(vp + 8);
      float pa = 0.f, pb = 0.f;
#pragma unroll
      for (int i = 0; i < 8; i++) {
        pa += qf[i] * bf2f((unsigned short)k0[i]);
        pb += qf[8 + i] * bf2f((unsigned short)k1[i]);
      }
      float p = pa + pb;
      p += __shfl_xor(p, 1); p += __shfl_xor(p, 2);
      p += __shfl_xor(p, 4); p += __shfl_xor(p, 8);
      float w = 0.f;
      if (valid) w = __expf(p * 0.0625f);
      wsum += w;
#pragma unroll
      for (int i = 0; i < 8; i++) {
        acc[i]     += w * bf2f((unsigned short)v0[i]);
        acc[8 + i] += w * bf2f((unsigned short)v1[i]);
      }
    }
    // combine the 4 groups (once per node)
    wsum += __shfl_xor(wsum, 16); wsum += __shfl_xor(wsum, 32);
#pragma unroll
    for (int i = 0; i < 16; i++) {
      acc[i] += __shfl_xor(acc[i], 16);
      acc[i] += __shfl_xor(acc[i], 32);
    }
    float inv = 1.f / fmaxf(wsum, 1e-16f);
    if (g == 0) {
      size_t idx = (size_t)n * 256 + sub * 16;
      s16x8 h0 = *(const s16x8*)(h + idx);
      s16x8 h1 = *(const s16x8*)(h + idx + 8);
      s16x8 r0, r1;
#pragma unroll
      for (int i = 0; i < 8; i++) {
        r0[i] = (short)f2bf(bf2f((unsigned short)h0[i]) + acc[i] * inv);
        r1[i] = (short)f2bf(bf2f((unsigned short)h1[i]) + acc[8 + i] * inv);
      }
      *(s16x8*)(h + idx) = r0;
      *(s16x8*)(h + idx + 8) = r1;
    }
  } else {  // dout == 128: 8 output dims per lane
    float acc[8];
#pragma unroll
    for (int i = 0; i < 8; i++) acc[i] = 0.f;
    int j = e0;
    for (; j + 4 <= e1; j += 4) {
      int s = __builtin_nontemporal_load(srcS + j + g);
      if (s < 0 || s >= Nn) s = 0;
      const ushort_t* kp = k + (size_t)s * 256 + sub * 16;
      const ushort_t* vp = v + (size_t)s * 128 + sub * 8;
      s16x8 k0 = *(const s16x8*)kp, k1 = *(const s16x8*)(kp + 8);
      s16x8 v0 = *(const s16x8*)vp;
      float pa = 0.f, pb = 0.f;
#pragma unroll
      for (int i = 0; i < 8; i++) {
        pa += qf[i] * bf2f((unsigned short)k0[i]);
        pb += qf[8 + i] * bf2f((unsigned short)k1[i]);
      }
      float p = pa + pb;
      p += __shfl_xor(p, 1); p += __shfl_xor(p, 2);
      p += __shfl_xor(p, 4); p += __shfl_xor(p, 8);
      float w = __expf(p * 0.0625f);
      wsum += w;
#pragma unroll
      for (int i = 0; i < 8; i++) acc[i] += w * bf2f((unsigned short)v0[i]);
    }
    int rem = e1 - j;
    if (rem > 0) {
      bool valid = g < rem;
      int s = __builtin_nontemporal_load(srcS + (valid ? (j + g) : j));
      if (s < 0 || s >= Nn) s = 0;
      const ushort_t* kp = k + (size_t)s * 256 + sub * 16;
      const ushort_t* vp = v + (size_t)s * 128 + sub * 8;
      s16x8 k0 = *(const s16x8*)kp, k1 = *(const s16x8*)(kp + 8);
      s16x8 v0 = *(const s16x8*)vp;
      float pa = 0.f, pb = 0.f;
#pragma unroll
      for (int i = 0; i < 8; i++) {
        pa += qf[i] * bf2f((unsigned short)k0[i]);
        pb += qf[8 + i] * bf2f((unsigned short)k1[i]);
      }
      float p = pa + pb;
      p += __shfl_xor(p, 1); p += __shfl_xor(p, 2);
      p += __shfl_xor(p, 4); p += __shfl_xor(p, 8);
      float w = 0.f;
      if (valid) w = __expf(p * 0.0625f);
      wsum += w;
#pragma unroll
      for (int i = 0; i < 8; i++) acc[i] += w * bf2f((unsigned short)v0[i]);
    }
    wsum += __shfl_xor(wsum, 16); wsum += __shfl_xor(wsum, 32);
#pragma unroll
    for (int i = 0; i < 8; i++) {
      acc[i] += __shfl_xor(acc[i], 16);
      acc[i] += __shfl_xor(acc[i], 32);
    }
    float inv = 1.f / fmaxf(wsum, 1e-16f);
    if (g == 0) {
      size_t idx = (size_t)n * 128 + sub * 8;
      s16x8 h0 = *(const s16x8*)(h + idx);
      s16x8 r0;
#pragma unroll
      for (int i = 0; i < 8; i++)
        r0[i] = (short)f2bf(bf2f((unsigned short)h0[i]) + acc[i] * inv);
      *(s16x8*)(h + idx) = r0;
    }
  }
}

// ---------------- BatchNorm ----------------
__global__ void bn_stats_kernel(const ushort_t* __restrict__ h, float* __restrict__ sum,
                                float* __restrict__ sumsq, int N, int F) {
  int col = threadIdx.x;
  float s = 0.f, s2 = 0.f;
  for (int r = blockIdx.x; r < N; r += gridDim.x) {
    float x = bf2f(h[(size_t)r * F + col]);
    s += x; s2 += x * x;
  }
  atomicAdd(&sum[col], s);
  atomicAdd(&sumsq[col], s2);
}

// normalize+relu; each block recomputes scale/shift from sums (removes bn_final launch)
__global__ void norm_relu_kernel(const ushort_t* __restrict__ h,
                                 const float* __restrict__ sum, const float* __restrict__ sumsq,
                                 const ushort_t* __restrict__ g, const ushort_t* __restrict__ be,
                                 ushort_t* __restrict__ x1, int N, size_t total, int cmask) {
  __shared__ float sc[256], sh[256];
  int t = threadIdx.x;
  if (t <= cmask) {
    float mu = sum[t] / (float)N;
    float var = sumsq[t] / (float)N - mu * mu;
    float s = bf2f(g[t]) * rsqrtf(var + 1e-5f);
    sc[t] = s;
    sh[t] = bf2f(be[t]) - mu * s;
  }
  __syncthreads();
  for (size_t i = blockIdx.x * (size_t)blockDim.x + t; i < total;
       i += (size_t)gridDim.x * blockDim.x) {
    int c = (int)(i & (size_t)cmask);
    float vv = bf2f(h[i]) * sc[c] + sh[c];
    x1[i] = f2bf(relu_nanprop(vv));
  }
}

// final: BN + residual + relu, dual-dtype out; recomputes scale/shift per block
__global__ void final_kernel(const ushort_t* __restrict__ h,
                             const float* __restrict__ sum, const float* __restrict__ sumsq,
                             const ushort_t* __restrict__ g, const ushort_t* __restrict__ be,
                             const ushort_t* __restrict__ x0b, void* __restrict__ out,
                             const int* __restrict__ flagF, int N, size_t total) {
  __shared__ float sc[128], sh[128];
  int t = threadIdx.x;
  if (t < 128) {
    float mu = sum[t] / (float)N;
    float var = sumsq[t] / (float)N - mu * mu;
    float s = bf2f(g[t]) * rsqrtf(var + 1e-5f);
    sc[t] = s;
    sh[t] = bf2f(be[t]) - mu * s;
  }
  __syncthreads();
  int f = flagF[0];
  for (size_t i = blockIdx.x * (size_t)blockDim.x + t; i < total;
       i += (size_t)gridDim.x * blockDim.x) {
    int c = (int)(i & 127);
    float vv = bf2f(h[i]) * sc[c] + sh[c] + bf2f(x0b[i]);
    vv = relu_nanprop(vv);
    if (f) ((float*)out)[i] = vv;
    else   ((ushort_t*)out)[i] = f2bf(vv);
  }
}

extern "C" void kernel_launch(void* const* d_in, const int* in_sizes, int n_in,
                              void* d_out, int out_size, void* d_ws, size_t ws_size,
                              hipStream_t stream) {
  const void* x0  = d_in[0];
  const void* edges = d_in[1];
  const void* Wq1 = d_in[2];
  const void* Wk1 = d_in[3];
  const void* Wv1 = d_in[4];
  const void* Wr1 = d_in[5];
  const void* b1  = d_in[6];
  const void* gw1 = d_in[7];
  const void* bw1 = d_in[8];
  const void* Wq2 = d_in[9];
  const void* Wk2 = d_in[10];
  const void* Wv2 = d_in[11];
  const void* Wr2 = d_in[12];
  const void* b2  = d_in[13];
  const void* gw2 = d_in[14];
  const void* bw2 = d_in[15];

  int N = in_sizes[0] / 128;
  int E = in_sizes[1] / 2;
  int NCHUNK = (N + 255) / 256;
  int MT = (N + 127) / 128;

  uintptr_t base = (uintptr_t)d_ws;
  auto carve = [&](size_t bytes) -> void* {
    uintptr_t p = base;
    base += (bytes + 255) & ~(size_t)255;
    return (void*)p;
  };
  ushort_t* x0b = (ushort_t*)carve((size_t)N * 128 * 2);
  ushort_t* qb = (ushort_t*)carve((size_t)N * 256 * 2);
  ushort_t* kb = (ushort_t*)carve((size_t)N * 256 * 2);
  ushort_t* vb = (ushort_t*)carve((size_t)N * 256 * 2);
  ushort_t* hb = (ushort_t*)carve((size_t)N * 256 * 2);
  ushort_t* x1 = (ushort_t*)carve((size_t)N * 256 * 2);
  ushort_t* wcat1 = (ushort_t*)carve((size_t)1024 * 128 * 2);
  ushort_t* wcat2 = (ushort_t*)carve((size_t)768 * 256 * 2);
  ushort_t* b1b  = (ushort_t*)carve(256 * 2);
  ushort_t* g1b  = (ushort_t*)carve(256 * 2);
  ushort_t* be1b = (ushort_t*)carve(256 * 2);
  ushort_t* b2b  = (ushort_t*)carve(128 * 2);
  ushort_t* g2b  = (ushort_t*)carve(128 * 2);
  ushort_t* be2b = (ushort_t*)carve(128 * 2);
  int* offs = (int*)carve((size_t)(N + 1) * 4);
  int* srcS = (int*)carve((size_t)E * 4);
  int* csum = (int*)carve(256 * 4);
  int* cpre = (int*)carve(256 * 4);
  // zeroed region: deg(N) fill(N) degS(N) fillS(N) sums(1024 floats)
  int nzero = 4 * N + 1024;
  int* zreg2 = (int*)carve((size_t)nzero * 4);
  int* deg   = zreg2;
  int* fill  = zreg2 + N;
  int* degS  = zreg2 + 2 * N;
  int* fillS = zreg2 + 3 * N;
  float* sum1 = (float*)(zreg2 + 4 * N);
  float* sq1  = sum1 + 256;
  float* sum2 = sum1 + 512;
  float* sq2  = sum1 + 640;
  int* eflag = (int*)carve(256);   // [0]=edge wide, [1]=float32 flag (setup writes)
  int* fF = eflag + 1;

  // R15: src-sorted intermediate arrays alias qb (only live BEFORE gemm4 writes qb).
  int* offsS = (int*)qb;                 // (N+1) ints
  int* esrc  = offsS + ((N + 64) & ~63); // E ints
  int* edst  = esrc + E;                 // E ints   (total ~6.6MB << 25.6MB)

  size_t needed = base - (uintptr_t)d_ws;
  if (needed > ws_size) return;

  // 1: zero + dtype detects
  setup_kernel<<<258, 256, 0, stream>>>(zreg2, N, (const int*)edges, 2 * E, eflag,
                                        (const unsigned int*)x0, N * 128, fF);
  // 2: x0 cvt + params + weight transposes + hist (dst AND src)
  cvt_all_kernel<<<6145, 256, 0, stream>>>(x0, x0b, N * 128,
                                           b1, gw1, bw1, b2, gw2, bw2,
                                           b1b, g1b, be1b, b2b, g2b, be2b,
                                           Wq1, Wk1, Wv1, Wr1, wcat1,
                                           Wq2, Wk2, Wv2, Wr2, wcat2,
                                           edges, deg, degS, E, N, eflag, fF);
  // 3a: src-CSR scan + bucket edges into exactly src-sorted (esrc, edst)
  chunk_sum_kernel<<<NCHUNK, 256, 0, stream>>>(degS, csum, N);
  scan_small_kernel<<<1, 256, 0, stream>>>(csum, cpre, NCHUNK, offsS, N);
  scan_final_kernel<<<NCHUNK, 256, 0, stream>>>(degS, cpre, offsS, N);
  scatterS_kernel<<<1024, 256, 0, stream>>>(edges, eflag, offsS, fillS, esrc, edst, E, N);
  // 3b: dst-CSR scan + fill from sorted stream (lists come out ~src-ascending)
  chunk_sum_kernel<<<NCHUNK, 256, 0, stream>>>(deg, csum, N);
  scan_small_kernel<<<1, 256, 0, stream>>>(csum, cpre, NCHUNK, offs, N);
  scan_final_kernel<<<NCHUNK, 256, 0, stream>>>(deg, cpre, offs, N);
  scatter2_kernel<<<1024, 256, 0, stream>>>(esrc, edst, offs, fill, srcS, E);

  dim3 gA1(MT, 8);   // x = M tile, y = col tile (R11 best)
  dim3 gA2(MT, 6);
  int gAttn = (N + 3) / 4;        // one wave per node
  // Layer 1
  gemm4_kernel<<<gA1, 256, 0, stream>>>(x0b, wcat1, qb, kb, vb, hb, b1b,
                                        N, 128, 1024, 256, 512, 768);
  attn_kernel<<<gAttn, 256, 0, stream>>>(qb, kb, vb, offs, srcS, hb, 256, N);
  bn_stats_kernel<<<512, 256, 0, stream>>>(hb, sum1, sq1, N, 256);
  norm_relu_kernel<<<4096, 256, 0, stream>>>(hb, sum1, sq1, g1b, be1b, x1, N,
                                             (size_t)N * 256, 255);
  // Layer 2
  gemm4_kernel<<<gA2, 256, 0, stream>>>(x1, wcat2, qb, kb, vb, hb, b2b,
                                        N, 256, 768, 256, 512, 640);
  attn_kernel<<<gAttn, 256, 0, stream>>>(qb, kb, vb, offs, srcS, hb, 128, N);
  bn_stats_kernel<<<512, 128, 0, stream>>>(hb, sum2, sq2, N, 128);
  final_kernel<<<4096, 256, 0, stream>>>(hb, sum2, sq2, g2b, be2b, x0b, d_out, fF, N,
                                         (size_t)N * 128);
}

// Round 3
// 587.416 us; speedup vs baseline: 1.1422x; 1.1422x over previous
//
#include <hip/hip_runtime.h>
#include <stdint.h>

typedef unsigned short ushort_t;

__device__ __forceinline__ float bf2f(unsigned short u) {
  union { unsigned int i; float f; } c; c.i = ((unsigned int)u) << 16; return c.f;
}
__device__ __forceinline__ unsigned short f2bf(float f) {
  union { float f; unsigned int i; } c; c.f = f;
  unsigned int r = c.i + 0x7FFFu + ((c.i >> 16) & 1u);
  return (unsigned short)(r >> 16);
}
// NaN-propagating relu (tripwire: NaN stays visible)
__device__ __forceinline__ float relu_nanprop(float v) { return (v < 0.f) ? 0.f : v; }

// async global->LDS 16B copy: LDS dest = wave-uniform base + lane*16 (HW-implicit)
__device__ __forceinline__ void async_copy16(const void* g, void* l) {
  __builtin_amdgcn_global_load_lds(
      (const __attribute__((address_space(1))) unsigned int*)(uintptr_t)g,
      (__attribute__((address_space(3))) unsigned int*)(uintptr_t)l,
      16, 0, 0);
}

typedef __attribute__((ext_vector_type(8))) short s16x8;
typedef __attribute__((ext_vector_type(4))) float f32x4;

__device__ __forceinline__ int edge_at(const void* edges, int wide, int idx) {
  if (wide) return (int)((const long long*)edges)[idx];
  return ((const int*)edges)[idx];
}

// ---------------- setup: zero scratch + dtype detects (1 launch) ----------------
__global__ void setup_kernel(int* __restrict__ zreg2, int N,
                             const int* __restrict__ e32, int n32, int* __restrict__ eflag,
                             const unsigned int* __restrict__ x, int nw, int* __restrict__ fF) {
  int b = blockIdx.x, tid = threadIdx.x;
  if (b < 256) {
    int total = 2 * N + 1024;
    for (int i = b * 256 + tid; i < total; i += 256 * 256) zreg2[i] = 0;
  } else if (b == 256) {
    __shared__ int any;
    if (tid == 0) any = 0;
    __syncthreads();
    for (int i = tid; i < 4096; i += 256) {
      int idx = 2 * i + 1;
      if (idx < n32 && e32[idx] != 0) any = 1;
    }
    __syncthreads();
    if (tid == 0) eflag[0] = (any == 0) ? 1 : 0;  // 1 => int64
  } else {
    __shared__ int cnt;
    if (tid == 0) cnt = 0;
    __syncthreads();
    int local = 0;
    for (int i = tid; i < 4096 && i < nw; i += 256) {
      unsigned int low = x[i] & 0xFFFFu;
      unsigned int e = (low >> 7) & 0xFFu;
      if (low != 0u && (e < 96u || e > 144u)) local++;
    }
    atomicAdd(&cnt, local);
    __syncthreads();
    if (tid == 0) fF[0] = (cnt > 1024) ? 1 : 0;  // 1 => float32 inputs
  }
}

// ---------------- cvt_all: x0 cvt + params + 2x weight transpose + hist (1 launch) ----
__global__ void cvt_all_kernel(const void* __restrict__ x0, ushort_t* __restrict__ x0b, int nx,
                               const void* p0, const void* p1, const void* p2,
                               const void* p3, const void* p4, const void* p5,
                               ushort_t* o0, ushort_t* o1, ushort_t* o2,
                               ushort_t* o3, ushort_t* o4, ushort_t* o5,
                               const void* W10, const void* W11, const void* W12, const void* W13,
                               ushort_t* __restrict__ wcat1,
                               const void* W20, const void* W21, const void* W22, const void* W23,
                               ushort_t* __restrict__ wcat2,
                               const void* __restrict__ edges, int* __restrict__ deg,
                               int E, int Nn,
                               const int* __restrict__ eflag, const int* __restrict__ fF) {
  int b = blockIdx.x, tid = threadIdx.x;
  int f = fF[0];
  if (b < 4096) {
    for (int i = b * 256 + tid; i < nx; i += 4096 * 256)
      x0b[i] = f ? f2bf(((const float*)x0)[i]) : ((const ushort_t*)x0)[i];
  } else if (b == 4096) {
    const void* ins[6] = {p0, p1, p2, p3, p4, p5};
    ushort_t* outs[6] = {o0, o1, o2, o3, o4, o5};
    const int segs[7] = {0, 256, 512, 768, 896, 1024, 1152};
    for (int i = tid; i < 1152; i += 256) {
      int s = 0;
      while (i >= segs[s + 1]) s++;
      int li = i - segs[s];
      outs[s][li] = f ? f2bf(((const float*)ins[s])[li]) : ((const ushort_t*)ins[s])[li];
    }
  } else if (b < 4609) {  // layer-1 weights: K=128, C=256 x4 -> wcat1[1024][128]
    const void* Ws[4] = {W10, W11, W12, W13};
    int per = 128 * 256, total = 4 * per;
    for (int i = (b - 4097) * 256 + tid; i < total; i += 512 * 256) {
      int wsel = i / per, rem = i - wsel * per;
      int k = rem >> 8, c = rem & 255;
      ushort_t v = f ? f2bf(((const float*)Ws[wsel])[rem]) : ((const ushort_t*)Ws[wsel])[rem];
      wcat1[(size_t)(wsel * 256 + c) * 128 + k] = v;
    }
  } else if (b < 5121) {  // layer-2 weights: K=256, C=256,256,128,128 -> wcat2[768][256]
    int per01 = 256 * 256, per23 = 256 * 128;
    int total = 2 * per01 + 2 * per23;
    for (int i = (b - 4609) * 256 + tid; i < total; i += 512 * 256) {
      const void* W; int rem, C, rowoff;
      if (i < per01)                 { W = W20; rem = i;                  C = 256; rowoff = 0; }
      else if (i < 2 * per01)        { W = W21; rem = i - per01;          C = 256; rowoff = 256; }
      else if (i < 2 * per01 + per23){ W = W22; rem = i - 2 * per01;      C = 128; rowoff = 512; }
      else                           { W = W23; rem = i - 2 * per01 - per23; C = 128; rowoff = 640; }
      int k = rem / C, c = rem - k * C;
      ushort_t v = f ? f2bf(((const float*)W)[rem]) : ((const ushort_t*)W)[rem];
      wcat2[(size_t)(rowoff + c) * 256 + k] = v;
    }
  } else {  // hist: 1024 blocks
    int wide = eflag[0];
    for (int e = (b - 5121) * 256 + tid; e < E; e += 1024 * 256) {
      int d = edge_at(edges, wide, E + e);
      if (d < 0) d = 0; if (d >= Nn) d = Nn - 1;
      atomicAdd(&deg[d], 1);
    }
  }
}

// 3-phase parallel scan (chunk = 256): supports N <= 65536
// [R13 post-mortem: single-kernel scan with per-block redundant prefix is a serial
// dependent-load chain (~195 iters in the last block) => ~+20us. Keep 3-phase.]
__global__ void chunk_sum_kernel(const int* __restrict__ deg, int* __restrict__ csum, int n) {
  int b = blockIdx.x, t = threadIdx.x, i = b * 256 + t;
  int v = (i < n) ? deg[i] : 0;
  __shared__ int ws[4];
#pragma unroll
  for (int o = 32; o > 0; o >>= 1) v += __shfl_down(v, o);
  if ((t & 63) == 0) ws[t >> 6] = v;
  __syncthreads();
  if (t == 0) csum[b] = ws[0] + ws[1] + ws[2] + ws[3];
}

__global__ void scan_small_kernel(const int* __restrict__ csum, int* __restrict__ cpre,
                                  int nc, int* __restrict__ offs, int N) {
  __shared__ int tmp[256];
  int t = threadIdx.x;
  int v = (t < nc) ? csum[t] : 0;
  tmp[t] = v;
  __syncthreads();
  for (int off = 1; off < 256; off <<= 1) {
    int x = (t >= off) ? tmp[t - off] : 0;
    __syncthreads();
    tmp[t] += x;
    __syncthreads();
  }
  if (t < nc) cpre[t] = tmp[t] - v;
  if (t == 255) offs[N] = tmp[255];
}

__global__ void scan_final_kernel(const int* __restrict__ deg, const int* __restrict__ cpre,
                                  int* __restrict__ offs, int n) {
  int b = blockIdx.x, t = threadIdx.x, i = b * 256 + t;
  __shared__ int tmp[256];
  int v = (i < n) ? deg[i] : 0;
  tmp[t] = v;
  __syncthreads();
  for (int off = 1; off < 256; off <<= 1) {
    int x = (t >= off) ? tmp[t - off] : 0;
    __syncthreads();
    tmp[t] += x;
    __syncthreads();
  }
  if (i < n) offs[i] = cpre[b] + tmp[t] - v;
}

__global__ void scatter_kernel(const void* __restrict__ edges, const int* __restrict__ flag,
                               const int* __restrict__ offs, int* __restrict__ fill,
                               int* __restrict__ srcS, int E, int Nn) {
  int wide = flag[0];
  for (int e = blockIdx.x * blockDim.x + threadIdx.x; e < E; e += gridDim.x * blockDim.x) {
    int s = edge_at(edges, wide, e);
    int d = edge_at(edges, wide, E + e);
    if (d < 0) d = 0; if (d >= Nn) d = Nn - 1;
    if (s < 0) s = 0; if (s >= Nn) s = Nn - 1;
    int p = offs[d] + atomicAdd(&fill[d], 1);
    if (p < 0) p = 0; if (p >= E) p = E - 1;
    srcS[p] = s;
  }
}

// ---------------- fused 4-way GEMM: [q|k|v|h] = A @ Wcat, bf16 in/out ----------------
// R11 config (best measured): 128x128 tile, acc 4x4, global_load_lds staging, grid
// x=M-tile / y=col-tile, hoisted-section SCALAR epilogue (fire-and-forget stores).
__global__ __launch_bounds__(256)
void gemm4_kernel(const ushort_t* __restrict__ A, const ushort_t* __restrict__ BT,
                  ushort_t* __restrict__ o0, ushort_t* __restrict__ o1,
                  ushort_t* __restrict__ o2, ushort_t* __restrict__ o3,
                  const ushort_t* __restrict__ bias3,
                  int M, int K, int NC, int b0, int b1, int b2) {
  __shared__ __align__(16) ushort_t As[128 * 32];
  __shared__ __align__(16) ushort_t Bs[128 * 32];
  int tid = threadIdx.x;
  int lane = tid & 63, wave = tid >> 6;
  int tm = blockIdx.x * 128, tn = blockIdx.y * 128;
  int wm = (wave >> 1) * 64, wn = (wave & 1) * 64;
  int q = lane >> 4, l = lane & 15;
  f32x4 acc[4][4];
#pragma unroll
  for (int a = 0; a < 4; a++)
#pragma unroll
    for (int b = 0; b < 4; b++) acc[a][b] = (f32x4){0.f, 0.f, 0.f, 0.f};

  int lrow = lane >> 2, c8 = (lane & 3) * 8;
  for (int k0 = 0; k0 < K; k0 += 32) {
#pragma unroll
    for (int t = 0; t < 2; t++) {
      int chunk = t * 4 + wave;           // 0..7, 16 rows each
      int row = chunk * 16 + lrow;
      int ra = tm + row; if (ra > M - 1) ra = M - 1;
      async_copy16(&A[(size_t)ra * K + k0 + c8], &As[chunk * 512]);
      async_copy16(&BT[(size_t)(tn + row) * K + k0 + c8], &Bs[chunk * 512]);
    }
    __syncthreads();
    s16x8 af[4], bfr[4];
#pragma unroll
    for (int mf = 0; mf < 4; mf++) af[mf] = *(const s16x8*)&As[(wm + mf * 16 + l) * 32 + q * 8];
#pragma unroll
    for (int nf = 0; nf < 4; nf++) bfr[nf] = *(const s16x8*)&Bs[(wn + nf * 16 + l) * 32 + q * 8];
#pragma unroll
    for (int mf = 0; mf < 4; mf++)
#pragma unroll
      for (int nf = 0; nf < 4; nf++)
        acc[mf][nf] = __builtin_amdgcn_mfma_f32_16x16x32_bf16(af[mf], bfr[nf], acc[mf][nf], 0, 0, 0);
    __syncthreads();
  }
  // Hoisted section select (tile is 128-aligned; sections are 128-multiples).
  ushort_t* op; int sbase, w; bool addb = false;
  if (tn < b0)      { op = o0; sbase = 0;  w = b0; }
  else if (tn < b1) { op = o1; sbase = b0; w = b1 - b0; }
  else if (tn < b2) { op = o2; sbase = b1; w = b2 - b1; }
  else              { op = o3; sbase = b2; w = NC - b2; addb = true; }
  int lc0 = tn + wn - sbase + l;
  float bv[4];
#pragma unroll
  for (int nf = 0; nf < 4; nf++) bv[nf] = addb ? bf2f(bias3[lc0 + nf * 16]) : 0.f;
  // C/D layout: col = lane&15, row = (lane>>4)*4 + reg   [m89-verified]
#pragma unroll
  for (int mf = 0; mf < 4; mf++) {
#pragma unroll
    for (int j = 0; j < 4; j++) {
      int r = tm + wm + mf * 16 + q * 4 + j;
      if (r < M) {
#pragma unroll
        for (int nf = 0; nf < 4; nf++)
          op[(size_t)r * w + lc0 + nf * 16] = f2bf(acc[mf][nf][j] + bv[nf]);
      }
    }
  }
}

// ---------------- fused attention + aggregation, one WAVE per dst node ----------------
// R14: 16-lane-per-edge groups (4 edges/wave-iter). Each lane owns 16 dims (32B).
// [R14 post-mortem: VALUBusy 54->36 but dur flat => fabric-latency/queue regime.]
// [R15 post-mortem: src-sorted CSR fill = zero FETCH delta (atomic arrival order
//  destroys sort; L3 already holds all data — L2/XCD 4MB is the miss source).]
// R16: 2-deep software pipeline — issue next 4 edges' srcS+K/V loads before doing
// current math. Doubles per-wave outstanding fabric requests (~4KB -> ~8KB).
__global__ __launch_bounds__(256)
void attn_kernel(const ushort_t* __restrict__ q, const ushort_t* __restrict__ k,
                 const ushort_t* __restrict__ v, const int* __restrict__ offs,
                 const int* __restrict__ srcS, ushort_t* __restrict__ h, int dout, int Nn) {
  int lane = threadIdx.x & 63, wave = threadIdx.x >> 6;
  int n = blockIdx.x * 4 + wave;
  if (n >= Nn) return;
  int g = lane >> 4, sub = lane & 15;

  // q: 16 dims per lane (all 4 groups hold the same dims for their own edge)
  s16x8 q0 = __builtin_nontemporal_load((const s16x8*)(q + (size_t)n * 256 + sub * 16));
  s16x8 q1 = __builtin_nontemporal_load((const s16x8*)(q + (size_t)n * 256 + sub * 16 + 8));
  float qf[16];
#pragma unroll
  for (int i = 0; i < 8; i++) {
    qf[i]     = bf2f((unsigned short)q0[i]);
    qf[8 + i] = bf2f((unsigned short)q1[i]);
  }

  int e0 = offs[n], e1 = offs[n + 1];
  float wsum = 0.f;

  if (dout == 256) {
    float acc[16];
#pragma unroll
    for (int i = 0; i < 16; i++) acc[i] = 0.f;
    int j = e0;
    s16x8 k0c, k1c, v0c, v1c;
    bool have = (j + 4 <= e1);
    if (have) {
      int s = __builtin_nontemporal_load(srcS + j + g);
      if (s < 0 || s >= Nn) s = 0;
      const ushort_t* kp = k + (size_t)s * 256 + sub * 16;
      const ushort_t* vp = v + (size_t)s * 256 + sub * 16;
      k0c = *(const s16x8*)kp; k1c = *(const s16x8*)(kp + 8);
      v0c = *(const s16x8*)vp; v1c = *(const s16x8*)(vp + 8);
    }
    for (; j + 8 <= e1; j += 4) {
      // issue next group's loads first (overlap with current math)
      int s2 = __builtin_nontemporal_load(srcS + j + 4 + g);
      if (s2 < 0 || s2 >= Nn) s2 = 0;
      const ushort_t* kp2 = k + (size_t)s2 * 256 + sub * 16;
      const ushort_t* vp2 = v + (size_t)s2 * 256 + sub * 16;
      s16x8 k0n = *(const s16x8*)kp2, k1n = *(const s16x8*)(kp2 + 8);
      s16x8 v0n = *(const s16x8*)vp2, v1n = *(const s16x8*)(vp2 + 8);
      // current math
      float pa = 0.f, pb = 0.f;
#pragma unroll
      for (int i = 0; i < 8; i++) {
        pa += qf[i] * bf2f((unsigned short)k0c[i]);
        pb += qf[8 + i] * bf2f((unsigned short)k1c[i]);
      }
      float p = pa + pb;
      p += __shfl_xor(p, 1); p += __shfl_xor(p, 2);
      p += __shfl_xor(p, 4); p += __shfl_xor(p, 8);
      float w = __expf(p * 0.0625f);
      wsum += w;
#pragma unroll
      for (int i = 0; i < 8; i++) {
        acc[i]     += w * bf2f((unsigned short)v0c[i]);
        acc[8 + i] += w * bf2f((unsigned short)v1c[i]);
      }
      k0c = k0n; k1c = k1n; v0c = v0n; v1c = v1n;
    }
    if (have) {
      float pa = 0.f, pb = 0.f;
#pragma unroll
      for (int i = 0; i < 8; i++) {
        pa += qf[i] * bf2f((unsigned short)k0c[i]);
        pb += qf[8 + i] * bf2f((unsigned short)k1c[i]);
      }
      float p = pa + pb;
      p += __shfl_xor(p, 1); p += __shfl_xor(p, 2);
      p += __shfl_xor(p, 4); p += __shfl_xor(p, 8);
      float w = __expf(p * 0.0625f);
      wsum += w;
#pragma unroll
      for (int i = 0; i < 8; i++) {
        acc[i]     += w * bf2f((unsigned short)v0c[i]);
        acc[8 + i] += w * bf2f((unsigned short)v1c[i]);
      }
      j += 4;
    }
    int rem = e1 - j;
    if (rem > 0) {
      bool valid = g < rem;
      int s = __builtin_nontemporal_load(srcS + (valid ? (j + g) : j));
      if (s < 0 || s >= Nn) s = 0;
      const ushort_t* kp = k + (size_t)s * 256 + sub * 16;
      const ushort_t* vp = v + (size_t)s * 256 + sub * 16;
      s16x8 k0 = *(const s16x8*)kp, k1 = *(const s16x8*)(kp + 8);
      s16x8 v0 = *(const s16x8*)vp, v1 = *(const s16x8*)(vp + 8);
      float pa = 0.f, pb = 0.f;
#pragma unroll
      for (int i = 0; i < 8; i++) {
        pa += qf[i] * bf2f((unsigned short)k0[i]);
        pb += qf[8 + i] * bf2f((unsigned short)k1[i]);
      }
      float p = pa + pb;
      p += __shfl_xor(p, 1); p += __shfl_xor(p, 2);
      p += __shfl_xor(p, 4); p += __shfl_xor(p, 8);
      float w = 0.f;
      if (valid) w = __expf(p * 0.0625f);
      wsum += w;
#pragma unroll
      for (int i = 0; i < 8; i++) {
        acc[i]     += w * bf2f((unsigned short)v0[i]);
        acc[8 + i] += w * bf2f((unsigned short)v1[i]);
      }
    }
    // combine the 4 groups (once per node)
    wsum += __shfl_xor(wsum, 16); wsum += __shfl_xor(wsum, 32);
#pragma unroll
    for (int i = 0; i < 16; i++) {
      acc[i] += __shfl_xor(acc[i], 16);
      acc[i] += __shfl_xor(acc[i], 32);
    }
    float inv = 1.f / fmaxf(wsum, 1e-16f);
    if (g == 0) {
      size_t idx = (size_t)n * 256 + sub * 16;
      s16x8 h0 = *(const s16x8*)(h + idx);
      s16x8 h1 = *(const s16x8*)(h + idx + 8);
      s16x8 r0, r1;
#pragma unroll
      for (int i = 0; i < 8; i++) {
        r0[i] = (short)f2bf(bf2f((unsigned short)h0[i]) + acc[i] * inv);
        r1[i] = (short)f2bf(bf2f((unsigned short)h1[i]) + acc[8 + i] * inv);
      }
      *(s16x8*)(h + idx) = r0;
      *(s16x8*)(h + idx + 8) = r1;
    }
  } else {  // dout == 128: 8 output dims per lane
    float acc[8];
#pragma unroll
    for (int i = 0; i < 8; i++) acc[i] = 0.f;
    int j = e0;
    s16x8 k0c, k1c, v0c;
    bool have = (j + 4 <= e1);
    if (have) {
      int s = __builtin_nontemporal_load(srcS + j + g);
      if (s < 0 || s >= Nn) s = 0;
      const ushort_t* kp = k + (size_t)s * 256 + sub * 16;
      const ushort_t* vp = v + (size_t)s * 128 + sub * 8;
      k0c = *(const s16x8*)kp; k1c = *(const s16x8*)(kp + 8);
      v0c = *(const s16x8*)vp;
    }
    for (; j + 8 <= e1; j += 4) {
      int s2 = __builtin_nontemporal_load(srcS + j + 4 + g);
      if (s2 < 0 || s2 >= Nn) s2 = 0;
      const ushort_t* kp2 = k + (size_t)s2 * 256 + sub * 16;
      const ushort_t* vp2 = v + (size_t)s2 * 128 + sub * 8;
      s16x8 k0n = *(const s16x8*)kp2, k1n = *(const s16x8*)(kp2 + 8);
      s16x8 v0n = *(const s16x8*)vp2;
      float pa = 0.f, pb = 0.f;
#pragma unroll
      for (int i = 0; i < 8; i++) {
        pa += qf[i] * bf2f((unsigned short)k0c[i]);
        pb += qf[8 + i] * bf2f((unsigned short)k1c[i]);
      }
      float p = pa + pb;
      p += __shfl_xor(p, 1); p += __shfl_xor(p, 2);
      p += __shfl_xor(p, 4); p += __shfl_xor(p, 8);
      float w = __expf(p * 0.0625f);
      wsum += w;
#pragma unroll
      for (int i = 0; i < 8; i++) acc[i] += w * bf2f((unsigned short)v0c[i]);
      k0c = k0n; k1c = k1n; v0c = v0n;
    }
    if (have) {
      float pa = 0.f, pb = 0.f;
#pragma unroll
      for (int i = 0; i < 8; i++) {
        pa += qf[i] * bf2f((unsigned short)k0c[i]);
        pb += qf[8 + i] * bf2f((unsigned short)k1c[i]);
      }
      float p = pa + pb;
      p += __shfl_xor(p, 1); p += __shfl_xor(p, 2);
      p += __shfl_xor(p, 4); p += __shfl_xor(p, 8);
      float w = __expf(p * 0.0625f);
      wsum += w;
#pragma unroll
      for (int i = 0; i < 8; i++) acc[i] += w * bf2f((unsigned short)v0c[i]);
      j += 4;
    }
    int rem = e1 - j;
    if (rem > 0) {
      bool valid = g < rem;
      int s = __builtin_nontemporal_load(srcS + (valid ? (j + g) : j));
      if (s < 0 || s >= Nn) s = 0;
      const ushort_t* kp = k + (size_t)s * 256 + sub * 16;
      const ushort_t* vp = v + (size_t)s * 128 + sub * 8;
      s16x8 k0 = *(const s16x8*)kp, k1 = *(const s16x8*)(kp + 8);
      s16x8 v0 = *(const s16x8*)vp;
      float pa = 0.f, pb = 0.f;
#pragma unroll
      for (int i = 0; i < 8; i++) {
        pa += qf[i] * bf2f((unsigned short)k0[i]);
        pb += qf[8 + i] * bf2f((unsigned short)k1[i]);
      }
      float p = pa + pb;
      p += __shfl_xor(p, 1); p += __shfl_xor(p, 2);
      p += __shfl_xor(p, 4); p += __shfl_xor(p, 8);
      float w = 0.f;
      if (valid) w = __expf(p * 0.0625f);
      wsum += w;
#pragma unroll
      for (int i = 0; i < 8; i++) acc[i] += w * bf2f((unsigned short)v0[i]);
    }
    wsum += __shfl_xor(wsum, 16); wsum += __shfl_xor(wsum, 32);
#pragma unroll
    for (int i = 0; i < 8; i++) {
      acc[i] += __shfl_xor(acc[i], 16);
      acc[i] += __shfl_xor(acc[i], 32);
    }
    float inv = 1.f / fmaxf(wsum, 1e-16f);
    if (g == 0) {
      size_t idx = (size_t)n * 128 + sub * 8;
      s16x8 h0 = *(const s16x8*)(h + idx);
      s16x8 r0;
#pragma unroll
      for (int i = 0; i < 8; i++)
        r0[i] = (short)f2bf(bf2f((unsigned short)h0[i]) + acc[i] * inv);
      *(s16x8*)(h + idx) = r0;
    }
  }
}

// ---------------- BatchNorm ----------------
__global__ void bn_stats_kernel(const ushort_t* __restrict__ h, float* __restrict__ sum,
                                float* __restrict__ sumsq, int N, int F) {
  int col = threadIdx.x;
  float s = 0.f, s2 = 0.f;
  for (int r = blockIdx.x; r < N; r += gridDim.x) {
    float x = bf2f(h[(size_t)r * F + col]);
    s += x; s2 += x * x;
  }
  atomicAdd(&sum[col], s);
  atomicAdd(&sumsq[col], s2);
}

// normalize+relu; each block recomputes scale/shift from sums (removes bn_final launch)
__global__ void norm_relu_kernel(const ushort_t* __restrict__ h,
                                 const float* __restrict__ sum, const float* __restrict__ sumsq,
                                 const ushort_t* __restrict__ g, const ushort_t* __restrict__ be,
                                 ushort_t* __restrict__ x1, int N, size_t total, int cmask) {
  __shared__ float sc[256], sh[256];
  int t = threadIdx.x;
  if (t <= cmask) {
    float mu = sum[t] / (float)N;
    float var = sumsq[t] / (float)N - mu * mu;
    float s = bf2f(g[t]) * rsqrtf(var + 1e-5f);
    sc[t] = s;
    sh[t] = bf2f(be[t]) - mu * s;
  }
  __syncthreads();
  for (size_t i = blockIdx.x * (size_t)blockDim.x + t; i < total;
       i += (size_t)gridDim.x * blockDim.x) {
    int c = (int)(i & (size_t)cmask);
    float vv = bf2f(h[i]) * sc[c] + sh[c];
    x1[i] = f2bf(relu_nanprop(vv));
  }
}

// final: BN + residual + relu, dual-dtype out; recomputes scale/shift per block
__global__ void final_kernel(const ushort_t* __restrict__ h,
                             const float* __restrict__ sum, const float* __restrict__ sumsq,
                             const ushort_t* __restrict__ g, const ushort_t* __restrict__ be,
                             const ushort_t* __restrict__ x0b, void* __restrict__ out,
                             const int* __restrict__ flagF, int N, size_t total) {
  __shared__ float sc[128], sh[128];
  int t = threadIdx.x;
  if (t < 128) {
    float mu = sum[t] / (float)N;
    float var = sumsq[t] / (float)N - mu * mu;
    float s = bf2f(g[t]) * rsqrtf(var + 1e-5f);
    sc[t] = s;
    sh[t] = bf2f(be[t]) - mu * s;
  }
  __syncthreads();
  int f = flagF[0];
  for (size_t i = blockIdx.x * (size_t)blockDim.x + t; i < total;
       i += (size_t)gridDim.x * blockDim.x) {
    int c = (int)(i & 127);
    float vv = bf2f(h[i]) * sc[c] + sh[c] + bf2f(x0b[i]);
    vv = relu_nanprop(vv);
    if (f) ((float*)out)[i] = vv;
    else   ((ushort_t*)out)[i] = f2bf(vv);
  }
}

extern "C" void kernel_launch(void* const* d_in, const int* in_sizes, int n_in,
                              void* d_out, int out_size, void* d_ws, size_t ws_size,
                              hipStream_t stream) {
  const void* x0  = d_in[0];
  const void* edges = d_in[1];
  const void* Wq1 = d_in[2];
  const void* Wk1 = d_in[3];
  const void* Wv1 = d_in[4];
  const void* Wr1 = d_in[5];
  const void* b1  = d_in[6];
  const void* gw1 = d_in[7];
  const void* bw1 = d_in[8];
  const void* Wq2 = d_in[9];
  const void* Wk2 = d_in[10];
  const void* Wv2 = d_in[11];
  const void* Wr2 = d_in[12];
  const void* b2  = d_in[13];
  const void* gw2 = d_in[14];
  const void* bw2 = d_in[15];

  int N = in_sizes[0] / 128;
  int E = in_sizes[1] / 2;
  int NCHUNK = (N + 255) / 256;
  int MT = (N + 127) / 128;

  uintptr_t base = (uintptr_t)d_ws;
  auto carve = [&](size_t bytes) -> void* {
    uintptr_t p = base;
    base += (bytes + 255) & ~(size_t)255;
    return (void*)p;
  };
  ushort_t* x0b = (ushort_t*)carve((size_t)N * 128 * 2);
  ushort_t* qb = (ushort_t*)carve((size_t)N * 256 * 2);
  ushort_t* kb = (ushort_t*)carve((size_t)N * 256 * 2);
  ushort_t* vb = (ushort_t*)carve((size_t)N * 256 * 2);
  ushort_t* hb = (ushort_t*)carve((size_t)N * 256 * 2);
  ushort_t* x1 = (ushort_t*)carve((size_t)N * 256 * 2);
  ushort_t* wcat1 = (ushort_t*)carve((size_t)1024 * 128 * 2);
  ushort_t* wcat2 = (ushort_t*)carve((size_t)768 * 256 * 2);
  ushort_t* b1b  = (ushort_t*)carve(256 * 2);
  ushort_t* g1b  = (ushort_t*)carve(256 * 2);
  ushort_t* be1b = (ushort_t*)carve(256 * 2);
  ushort_t* b2b  = (ushort_t*)carve(128 * 2);
  ushort_t* g2b  = (ushort_t*)carve(128 * 2);
  ushort_t* be2b = (ushort_t*)carve(128 * 2);
  int* offs = (int*)carve((size_t)(N + 1) * 4);
  int* srcS = (int*)carve((size_t)E * 4);
  int* csum = (int*)carve(256 * 4);
  int* cpre = (int*)carve(256 * 4);
  // zeroed region: deg(N) fill(N) sums(1024 floats)
  int nzero = 2 * N + 1024;
  int* zreg2 = (int*)carve((size_t)nzero * 4);
  int* deg   = zreg2;
  int* fill  = zreg2 + N;
  float* sum1 = (float*)(zreg2 + 2 * N);
  float* sq1  = sum1 + 256;
  float* sum2 = sum1 + 512;
  float* sq2  = sum1 + 640;
  int* eflag = (int*)carve(256);   // [0]=edge wide, [1]=float32 flag (setup writes)
  int* fF = eflag + 1;

  size_t needed = base - (uintptr_t)d_ws;
  if (needed > ws_size) return;

  // 1: zero + dtype detects
  setup_kernel<<<258, 256, 0, stream>>>(zreg2, N, (const int*)edges, 2 * E, eflag,
                                        (const unsigned int*)x0, N * 128, fF);
  // 2: x0 cvt + params + weight transposes + hist
  cvt_all_kernel<<<6145, 256, 0, stream>>>(x0, x0b, N * 128,
                                           b1, gw1, bw1, b2, gw2, bw2,
                                           b1b, g1b, be1b, b2b, g2b, be2b,
                                           Wq1, Wk1, Wv1, Wr1, wcat1,
                                           Wq2, Wk2, Wv2, Wr2, wcat2,
                                           edges, deg, E, N, eflag, fF);
  // 3-6: scan + scatter
  chunk_sum_kernel<<<NCHUNK, 256, 0, stream>>>(deg, csum, N);
  scan_small_kernel<<<1, 256, 0, stream>>>(csum, cpre, NCHUNK, offs, N);
  scan_final_kernel<<<NCHUNK, 256, 0, stream>>>(deg, cpre, offs, N);
  scatter_kernel<<<1024, 256, 0, stream>>>(edges, eflag, offs, fill, srcS, E, N);

  dim3 gA1(MT, 8);   // x = M tile, y = col tile (R11 best)
  dim3 gA2(MT, 6);
  int gAttn = (N + 3) / 4;        // one wave per node
  // Layer 1
  gemm4_kernel<<<gA1, 256, 0, stream>>>(x0b, wcat1, qb, kb, vb, hb, b1b,
                                        N, 128, 1024, 256, 512, 768);
  attn_kernel<<<gAttn, 256, 0, stream>>>(qb, kb, vb, offs, srcS, hb, 256, N);
  bn_stats_kernel<<<512, 256, 0, stream>>>(hb, sum1, sq1, N, 256);
  norm_relu_kernel<<<4096, 256, 0, stream>>>(hb, sum1, sq1, g1b, be1b, x1, N,
                                             (size_t)N * 256, 255);
  // Layer 2
  gemm4_kernel<<<gA2, 256, 0, stream>>>(x1, wcat2, qb, kb, vb, hb, b2b,
                                        N, 256, 768, 256, 512, 640);
  attn_kernel<<<gAttn, 256, 0, stream>>>(qb, kb, vb, offs, srcS, hb, 128, N);
  bn_stats_kernel<<<512, 128, 0, stream>>>(hb, sum2, sq2, N, 128);
  final_kernel<<<4096, 256, 0, stream>>>(hb, sum2, sq2, g2b, be2b, x0b, d_out, fF, N,
                                         (size_t)N * 128);
}

// Round 4
// 547.361 us; speedup vs baseline: 1.2258x; 1.0732x over previous
//
#include <hip/hip_runtime.h>
#include <stdint.h>

typedef unsigned short ushort_t;

__device__ __forceinline__ float bf2f(unsigned short u) {
  union { unsigned int i; float f; } c; c.i = ((unsigned int)u) << 16; return c.f;
}
__device__ __forceinline__ unsigned short f2bf(float f) {
  union { float f; unsigned int i; } c; c.f = f;
  unsigned int r = c.i + 0x7FFFu + ((c.i >> 16) & 1u);
  return (unsigned short)(r >> 16);
}
// NaN-propagating relu (tripwire: NaN stays visible)
__device__ __forceinline__ float relu_nanprop(float v) { return (v < 0.f) ? 0.f : v; }

// async global->LDS 16B copy: LDS dest = wave-uniform base + lane*16 (HW-implicit)
__device__ __forceinline__ void async_copy16(const void* g, void* l) {
  __builtin_amdgcn_global_load_lds(
      (const __attribute__((address_space(1))) unsigned int*)(uintptr_t)g,
      (__attribute__((address_space(3))) unsigned int*)(uintptr_t)l,
      16, 0, 0);
}

typedef __attribute__((ext_vector_type(8))) short s16x8;
typedef __attribute__((ext_vector_type(4))) float f32x4;

__device__ __forceinline__ int edge_at(const void* edges, int wide, int idx) {
  if (wide) return (int)((const long long*)edges)[idx];
  return ((const int*)edges)[idx];
}

// ---------------- setup: zero scratch + dtype detects (1 launch) ----------------
__global__ void setup_kernel(int* __restrict__ zreg2, int N,
                             const int* __restrict__ e32, int n32, int* __restrict__ eflag,
                             const unsigned int* __restrict__ x, int nw, int* __restrict__ fF) {
  int b = blockIdx.x, tid = threadIdx.x;
  if (b < 256) {
    int total = 2 * N + 1024;
    for (int i = b * 256 + tid; i < total; i += 256 * 256) zreg2[i] = 0;
  } else if (b == 256) {
    __shared__ int any;
    if (tid == 0) any = 0;
    __syncthreads();
    for (int i = tid; i < 4096; i += 256) {
      int idx = 2 * i + 1;
      if (idx < n32 && e32[idx] != 0) any = 1;
    }
    __syncthreads();
    if (tid == 0) eflag[0] = (any == 0) ? 1 : 0;  // 1 => int64
  } else {
    __shared__ int cnt;
    if (tid == 0) cnt = 0;
    __syncthreads();
    int local = 0;
    for (int i = tid; i < 4096 && i < nw; i += 256) {
      unsigned int low = x[i] & 0xFFFFu;
      unsigned int e = (low >> 7) & 0xFFu;
      if (low != 0u && (e < 96u || e > 144u)) local++;
    }
    atomicAdd(&cnt, local);
    __syncthreads();
    if (tid == 0) fF[0] = (cnt > 1024) ? 1 : 0;  // 1 => float32 inputs
  }
}

// ---------------- cvt_all: x0 cvt + params + weight prep + hist (1 launch) ----------
// R17: layer weights now prepared for the qt-factorization:
//  Wq*b / Wk*b: straight bf16 copies (inputs to on-device M = Wk @ Wq^T GEMM)
//  wcatB* rows [D..]: Wr^T   (gemm4a B-matrix tail; rows [0..D) filled by M-GEMM)
//  wcatV*: Wv^T              (post-attn accumulate GEMM)
__global__ void cvt_all_kernel(const void* __restrict__ x0, ushort_t* __restrict__ x0b, int nx,
                               const void* p0, const void* p1, const void* p2,
                               const void* p3, const void* p4, const void* p5,
                               ushort_t* o0, ushort_t* o1, ushort_t* o2,
                               ushort_t* o3, ushort_t* o4, ushort_t* o5,
                               const void* W10, const void* W11, const void* W12, const void* W13,
                               ushort_t* __restrict__ Wq1b, ushort_t* __restrict__ Wk1b,
                               ushort_t* __restrict__ wcatB1, ushort_t* __restrict__ wcatV1,
                               const void* W20, const void* W21, const void* W22, const void* W23,
                               ushort_t* __restrict__ Wq2b, ushort_t* __restrict__ Wk2b,
                               ushort_t* __restrict__ wcatB2, ushort_t* __restrict__ wcatV2,
                               const void* __restrict__ edges, int* __restrict__ deg,
                               int E, int Nn,
                               const int* __restrict__ eflag, const int* __restrict__ fF) {
  int b = blockIdx.x, tid = threadIdx.x;
  int f = fF[0];
  if (b < 4096) {
    for (int i = b * 256 + tid; i < nx; i += 4096 * 256)
      x0b[i] = f ? f2bf(((const float*)x0)[i]) : ((const ushort_t*)x0)[i];
  } else if (b == 4096) {
    const void* ins[6] = {p0, p1, p2, p3, p4, p5};
    ushort_t* outs[6] = {o0, o1, o2, o3, o4, o5};
    const int segs[7] = {0, 256, 512, 768, 896, 1024, 1152};
    for (int i = tid; i < 1152; i += 256) {
      int s = 0;
      while (i >= segs[s + 1]) s++;
      int li = i - segs[s];
      outs[s][li] = f ? f2bf(((const float*)ins[s])[li]) : ((const ushort_t*)ins[s])[li];
    }
  } else if (b < 4609) {
    // layer-1: Wq1[128][256], Wk1[128][256] straight; Wr1[128][256]->wcatB1 rows 128..383;
    // Wv1[128][256]->wcatV1[256][128]. total 131072 elems.
    for (int i = (b - 4097) * 256 + tid; i < 131072; i += 512 * 256) {
      if (i < 32768) {
        Wq1b[i] = f ? f2bf(((const float*)W10)[i]) : ((const ushort_t*)W10)[i];
      } else if (i < 65536) {
        int r = i - 32768;
        Wk1b[r] = f ? f2bf(((const float*)W11)[r]) : ((const ushort_t*)W11)[r];
      } else if (i < 98304) {
        int rem = i - 65536, k = rem >> 8, c = rem & 255;  // Wr1[k][c]
        ushort_t v = f ? f2bf(((const float*)W13)[rem]) : ((const ushort_t*)W13)[rem];
        wcatB1[(size_t)(128 + c) * 128 + k] = v;
      } else {
        int rem = i - 98304, k = rem >> 8, c = rem & 255;  // Wv1[k][c]
        ushort_t v = f ? f2bf(((const float*)W12)[rem]) : ((const ushort_t*)W12)[rem];
        wcatV1[(size_t)c * 128 + k] = v;
      }
    }
  } else if (b < 5121) {
    // layer-2: Wq2[256][256], Wk2[256][256] straight; Wr2[256][128]->wcatB2 rows 256..383;
    // Wv2[256][128]->wcatV2[128][256]. total 196608 elems.
    for (int i = (b - 4609) * 256 + tid; i < 196608; i += 512 * 256) {
      if (i < 65536) {
        Wq2b[i] = f ? f2bf(((const float*)W20)[i]) : ((const ushort_t*)W20)[i];
      } else if (i < 131072) {
        int r = i - 65536;
        Wk2b[r] = f ? f2bf(((const float*)W21)[r]) : ((const ushort_t*)W21)[r];
      } else if (i < 163840) {
        int rem = i - 131072, k = rem >> 7, c = rem & 127;  // Wr2[k][c]
        ushort_t v = f ? f2bf(((const float*)W23)[rem]) : ((const ushort_t*)W23)[rem];
        wcatB2[(size_t)(256 + c) * 256 + k] = v;
      } else {
        int rem = i - 163840, k = rem >> 7, c = rem & 127;  // Wv2[k][c]
        ushort_t v = f ? f2bf(((const float*)W22)[rem]) : ((const ushort_t*)W22)[rem];
        wcatV2[(size_t)c * 256 + k] = v;
      }
    }
  } else {  // hist: 1024 blocks
    int wide = eflag[0];
    for (int e = (b - 5121) * 256 + tid; e < E; e += 1024 * 256) {
      int d = edge_at(edges, wide, E + e);
      if (d < 0) d = 0; if (d >= Nn) d = Nn - 1;
      atomicAdd(&deg[d], 1);
    }
  }
}

// 3-phase parallel scan (chunk = 256): supports N <= 65536
__global__ void chunk_sum_kernel(const int* __restrict__ deg, int* __restrict__ csum, int n) {
  int b = blockIdx.x, t = threadIdx.x, i = b * 256 + t;
  int v = (i < n) ? deg[i] : 0;
  __shared__ int ws[4];
#pragma unroll
  for (int o = 32; o > 0; o >>= 1) v += __shfl_down(v, o);
  if ((t & 63) == 0) ws[t >> 6] = v;
  __syncthreads();
  if (t == 0) csum[b] = ws[0] + ws[1] + ws[2] + ws[3];
}

__global__ void scan_small_kernel(const int* __restrict__ csum, int* __restrict__ cpre,
                                  int nc, int* __restrict__ offs, int N) {
  __shared__ int tmp[256];
  int t = threadIdx.x;
  int v = (t < nc) ? csum[t] : 0;
  tmp[t] = v;
  __syncthreads();
  for (int off = 1; off < 256; off <<= 1) {
    int x = (t >= off) ? tmp[t - off] : 0;
    __syncthreads();
    tmp[t] += x;
    __syncthreads();
  }
  if (t < nc) cpre[t] = tmp[t] - v;
  if (t == 255) offs[N] = tmp[255];
}

__global__ void scan_final_kernel(const int* __restrict__ deg, const int* __restrict__ cpre,
                                  int* __restrict__ offs, int n) {
  int b = blockIdx.x, t = threadIdx.x, i = b * 256 + t;
  __shared__ int tmp[256];
  int v = (i < n) ? deg[i] : 0;
  tmp[t] = v;
  __syncthreads();
  for (int off = 1; off < 256; off <<= 1) {
    int x = (t >= off) ? tmp[t - off] : 0;
    __syncthreads();
    tmp[t] += x;
    __syncthreads();
  }
  if (i < n) offs[i] = cpre[b] + tmp[t] - v;
}

__global__ void scatter_kernel(const void* __restrict__ edges, const int* __restrict__ flag,
                               const int* __restrict__ offs, int* __restrict__ fill,
                               int* __restrict__ srcS, int E, int Nn) {
  int wide = flag[0];
  for (int e = blockIdx.x * blockDim.x + threadIdx.x; e < E; e += gridDim.x * blockDim.x) {
    int s = edge_at(edges, wide, e);
    int d = edge_at(edges, wide, E + e);
    if (d < 0) d = 0; if (d >= Nn) d = Nn - 1;
    if (s < 0) s = 0; if (s >= Nn) s = Nn - 1;
    int p = offs[d] + atomicAdd(&fill[d], 1);
    if (p < 0) p = 0; if (p >= E) p = E - 1;
    srcS[p] = s;
  }
}

// ---------------- fused multi-section GEMM: out = A @ Bcat (+bias) (+accum) --------
// R11 config (best measured): 128x128 tile, acc 4x4, global_load_lds staging.
// R17: added accum flag (epilogue read-modify-write) for the deferred-Wv GEMM.
__global__ __launch_bounds__(256)
void gemm4_kernel(const ushort_t* __restrict__ A, const ushort_t* __restrict__ BT,
                  ushort_t* __restrict__ o0, ushort_t* __restrict__ o1,
                  ushort_t* __restrict__ o2, ushort_t* __restrict__ o3,
                  const ushort_t* __restrict__ bias3,
                  int M, int K, int NC, int b0, int b1, int b2, int accum) {
  __shared__ __align__(16) ushort_t As[128 * 32];
  __shared__ __align__(16) ushort_t Bs[128 * 32];
  int tid = threadIdx.x;
  int lane = tid & 63, wave = tid >> 6;
  int tm = blockIdx.x * 128, tn = blockIdx.y * 128;
  int wm = (wave >> 1) * 64, wn = (wave & 1) * 64;
  int q = lane >> 4, l = lane & 15;
  f32x4 acc[4][4];
#pragma unroll
  for (int a = 0; a < 4; a++)
#pragma unroll
    for (int b = 0; b < 4; b++) acc[a][b] = (f32x4){0.f, 0.f, 0.f, 0.f};

  int lrow = lane >> 2, c8 = (lane & 3) * 8;
  for (int k0 = 0; k0 < K; k0 += 32) {
#pragma unroll
    for (int t = 0; t < 2; t++) {
      int chunk = t * 4 + wave;           // 0..7, 16 rows each
      int row = chunk * 16 + lrow;
      int ra = tm + row; if (ra > M - 1) ra = M - 1;
      async_copy16(&A[(size_t)ra * K + k0 + c8], &As[chunk * 512]);
      async_copy16(&BT[(size_t)(tn + row) * K + k0 + c8], &Bs[chunk * 512]);
    }
    __syncthreads();
    s16x8 af[4], bfr[4];
#pragma unroll
    for (int mf = 0; mf < 4; mf++) af[mf] = *(const s16x8*)&As[(wm + mf * 16 + l) * 32 + q * 8];
#pragma unroll
    for (int nf = 0; nf < 4; nf++) bfr[nf] = *(const s16x8*)&Bs[(wn + nf * 16 + l) * 32 + q * 8];
#pragma unroll
    for (int mf = 0; mf < 4; mf++)
#pragma unroll
      for (int nf = 0; nf < 4; nf++)
        acc[mf][nf] = __builtin_amdgcn_mfma_f32_16x16x32_bf16(af[mf], bfr[nf], acc[mf][nf], 0, 0, 0);
    __syncthreads();
  }
  // Hoisted section select (tile is 128-aligned; sections are 128-multiples).
  ushort_t* op; int sbase, w; bool addb = false;
  if (tn < b0)      { op = o0; sbase = 0;  w = b0; }
  else if (tn < b1) { op = o1; sbase = b0; w = b1 - b0; }
  else if (tn < b2) { op = o2; sbase = b1; w = b2 - b1; }
  else              { op = o3; sbase = b2; w = NC - b2; addb = true; }
  int lc0 = tn + wn - sbase + l;
  float bv[4];
#pragma unroll
  for (int nf = 0; nf < 4; nf++) bv[nf] = addb ? bf2f(bias3[lc0 + nf * 16]) : 0.f;
  // C/D layout: col = lane&15, row = (lane>>4)*4 + reg   [m89-verified]
#pragma unroll
  for (int mf = 0; mf < 4; mf++) {
#pragma unroll
    for (int j = 0; j < 4; j++) {
      int r = tm + wm + mf * 16 + q * 4 + j;
      if (r < M) {
#pragma unroll
        for (int nf = 0; nf < 4; nf++) {
          size_t idx = (size_t)r * w + lc0 + nf * 16;
          float prev = accum ? bf2f(op[idx]) : 0.f;
          op[idx] = f2bf(acc[mf][nf][j] + bv[nf] + prev);
        }
      }
    }
  }
}

// ---------------- fused attention + aggregation, one WAVE per dst node ----------------
// R17: qt-factorization. logit = qt[d]·x[s]; agg = sum(w * x[s]) (Wv applied after by
// GEMM). ONE gather per edge serves both dot and accumulation: 256B/edge (D=128) or
// 512B/edge (D=256) vs 1024/768B before.
// [R14: 16-lane groups, 4 edges/wave-iter. R16 pipeline removed: no effect, cost occ.]
__global__ __launch_bounds__(256)
void attn_kernel(const ushort_t* __restrict__ qt, const ushort_t* __restrict__ x,
                 const int* __restrict__ offs, const int* __restrict__ srcS,
                 ushort_t* __restrict__ aggb, int D, int Nn) {
  int lane = threadIdx.x & 63, wave = threadIdx.x >> 6;
  int n = blockIdx.x * 4 + wave;
  if (n >= Nn) return;
  int g = lane >> 4, sub = lane & 15;

  int e0 = offs[n], e1 = offs[n + 1];
  float wsum = 0.f;

  if (D == 128) {  // 8 dims per lane
    s16x8 qv = __builtin_nontemporal_load((const s16x8*)(qt + (size_t)n * 128 + sub * 8));
    float qf[8];
#pragma unroll
    for (int i = 0; i < 8; i++) qf[i] = bf2f((unsigned short)qv[i]);
    float acc[8];
#pragma unroll
    for (int i = 0; i < 8; i++) acc[i] = 0.f;
    int j = e0;
    for (; j + 4 <= e1; j += 4) {
      int s = __builtin_nontemporal_load(srcS + j + g);
      if (s < 0 || s >= Nn) s = 0;
      s16x8 xv = *(const s16x8*)(x + (size_t)s * 128 + sub * 8);
      float p = 0.f;
#pragma unroll
      for (int i = 0; i < 8; i++) p += qf[i] * bf2f((unsigned short)xv[i]);
      p += __shfl_xor(p, 1); p += __shfl_xor(p, 2);
      p += __shfl_xor(p, 4); p += __shfl_xor(p, 8);
      float w = __expf(p * 0.0625f);
      wsum += w;
#pragma unroll
      for (int i = 0; i < 8; i++) acc[i] += w * bf2f((unsigned short)xv[i]);
    }
    int rem = e1 - j;
    if (rem > 0) {
      bool valid = g < rem;
      int s = __builtin_nontemporal_load(srcS + (valid ? (j + g) : j));
      if (s < 0 || s >= Nn) s = 0;
      s16x8 xv = *(const s16x8*)(x + (size_t)s * 128 + sub * 8);
      float p = 0.f;
#pragma unroll
      for (int i = 0; i < 8; i++) p += qf[i] * bf2f((unsigned short)xv[i]);
      p += __shfl_xor(p, 1); p += __shfl_xor(p, 2);
      p += __shfl_xor(p, 4); p += __shfl_xor(p, 8);
      float w = 0.f;
      if (valid) w = __expf(p * 0.0625f);
      wsum += w;
#pragma unroll
      for (int i = 0; i < 8; i++) acc[i] += w * bf2f((unsigned short)xv[i]);
    }
    wsum += __shfl_xor(wsum, 16); wsum += __shfl_xor(wsum, 32);
#pragma unroll
    for (int i = 0; i < 8; i++) {
      acc[i] += __shfl_xor(acc[i], 16);
      acc[i] += __shfl_xor(acc[i], 32);
    }
    float inv = 1.f / fmaxf(wsum, 1e-16f);
    if (g == 0) {
      s16x8 r0;
#pragma unroll
      for (int i = 0; i < 8; i++) r0[i] = (short)f2bf(acc[i] * inv);
      *(s16x8*)(aggb + (size_t)n * 128 + sub * 8) = r0;
    }
  } else {  // D == 256: 16 dims per lane
    s16x8 q0 = __builtin_nontemporal_load((const s16x8*)(qt + (size_t)n * 256 + sub * 16));
    s16x8 q1 = __builtin_nontemporal_load((const s16x8*)(qt + (size_t)n * 256 + sub * 16 + 8));
    float qf[16];
#pragma unroll
    for (int i = 0; i < 8; i++) {
      qf[i]     = bf2f((unsigned short)q0[i]);
      qf[8 + i] = bf2f((unsigned short)q1[i]);
    }
    float acc[16];
#pragma unroll
    for (int i = 0; i < 16; i++) acc[i] = 0.f;
    int j = e0;
    for (; j + 4 <= e1; j += 4) {
      int s = __builtin_nontemporal_load(srcS + j + g);
      if (s < 0 || s >= Nn) s = 0;
      const ushort_t* xp = x + (size_t)s * 256 + sub * 16;
      s16x8 x0v = *(const s16x8*)xp, x1v = *(const s16x8*)(xp + 8);
      float pa = 0.f, pb = 0.f;
#pragma unroll
      for (int i = 0; i < 8; i++) {
        pa += qf[i] * bf2f((unsigned short)x0v[i]);
        pb += qf[8 + i] * bf2f((unsigned short)x1v[i]);
      }
      float p = pa + pb;
      p += __shfl_xor(p, 1); p += __shfl_xor(p, 2);
      p += __shfl_xor(p, 4); p += __shfl_xor(p, 8);
      float w = __expf(p * 0.0625f);
      wsum += w;
#pragma unroll
      for (int i = 0; i < 8; i++) {
        acc[i]     += w * bf2f((unsigned short)x0v[i]);
        acc[8 + i] += w * bf2f((unsigned short)x1v[i]);
      }
    }
    int rem = e1 - j;
    if (rem > 0) {
      bool valid = g < rem;
      int s = __builtin_nontemporal_load(srcS + (valid ? (j + g) : j));
      if (s < 0 || s >= Nn) s = 0;
      const ushort_t* xp = x + (size_t)s * 256 + sub * 16;
      s16x8 x0v = *(const s16x8*)xp, x1v = *(const s16x8*)(xp + 8);
      float pa = 0.f, pb = 0.f;
#pragma unroll
      for (int i = 0; i < 8; i++) {
        pa += qf[i] * bf2f((unsigned short)x0v[i]);
        pb += qf[8 + i] * bf2f((unsigned short)x1v[i]);
      }
      float p = pa + pb;
      p += __shfl_xor(p, 1); p += __shfl_xor(p, 2);
      p += __shfl_xor(p, 4); p += __shfl_xor(p, 8);
      float w = 0.f;
      if (valid) w = __expf(p * 0.0625f);
      wsum += w;
#pragma unroll
      for (int i = 0; i < 8; i++) {
        acc[i]     += w * bf2f((unsigned short)x0v[i]);
        acc[8 + i] += w * bf2f((unsigned short)x1v[i]);
      }
    }
    wsum += __shfl_xor(wsum, 16); wsum += __shfl_xor(wsum, 32);
#pragma unroll
    for (int i = 0; i < 16; i++) {
      acc[i] += __shfl_xor(acc[i], 16);
      acc[i] += __shfl_xor(acc[i], 32);
    }
    float inv = 1.f / fmaxf(wsum, 1e-16f);
    if (g == 0) {
      s16x8 r0, r1;
#pragma unroll
      for (int i = 0; i < 8; i++) {
        r0[i] = (short)f2bf(acc[i] * inv);
        r1[i] = (short)f2bf(acc[8 + i] * inv);
      }
      size_t idx = (size_t)n * 256 + sub * 16;
      *(s16x8*)(aggb + idx) = r0;
      *(s16x8*)(aggb + idx + 8) = r1;
    }
  }
}

// ---------------- BatchNorm ----------------
__global__ void bn_stats_kernel(const ushort_t* __restrict__ h, float* __restrict__ sum,
                                float* __restrict__ sumsq, int N, int F) {
  int col = threadIdx.x;
  float s = 0.f, s2 = 0.f;
  for (int r = blockIdx.x; r < N; r += gridDim.x) {
    float x = bf2f(h[(size_t)r * F + col]);
    s += x; s2 += x * x;
  }
  atomicAdd(&sum[col], s);
  atomicAdd(&sumsq[col], s2);
}

// normalize+relu; each block recomputes scale/shift from sums (removes bn_final launch)
__global__ void norm_relu_kernel(const ushort_t* __restrict__ h,
                                 const float* __restrict__ sum, const float* __restrict__ sumsq,
                                 const ushort_t* __restrict__ g, const ushort_t* __restrict__ be,
                                 ushort_t* __restrict__ x1, int N, size_t total, int cmask) {
  __shared__ float sc[256], sh[256];
  int t = threadIdx.x;
  if (t <= cmask) {
    float mu = sum[t] / (float)N;
    float var = sumsq[t] / (float)N - mu * mu;
    float s = bf2f(g[t]) * rsqrtf(var + 1e-5f);
    sc[t] = s;
    sh[t] = bf2f(be[t]) - mu * s;
  }
  __syncthreads();
  for (size_t i = blockIdx.x * (size_t)blockDim.x + t; i < total;
       i += (size_t)gridDim.x * blockDim.x) {
    int c = (int)(i & (size_t)cmask);
    float vv = bf2f(h[i]) * sc[c] + sh[c];
    x1[i] = f2bf(relu_nanprop(vv));
  }
}

// final: BN + residual + relu, dual-dtype out; recomputes scale/shift per block
__global__ void final_kernel(const ushort_t* __restrict__ h,
                             const float* __restrict__ sum, const float* __restrict__ sumsq,
                             const ushort_t* __restrict__ g, const ushort_t* __restrict__ be,
                             const ushort_t* __restrict__ x0b, void* __restrict__ out,
                             const int* __restrict__ flagF, int N, size_t total) {
  __shared__ float sc[128], sh[128];
  int t = threadIdx.x;
  if (t < 128) {
    float mu = sum[t] / (float)N;
    float var = sumsq[t] / (float)N - mu * mu;
    float s = bf2f(g[t]) * rsqrtf(var + 1e-5f);
    sc[t] = s;
    sh[t] = bf2f(be[t]) - mu * s;
  }
  __syncthreads();
  int f = flagF[0];
  for (size_t i = blockIdx.x * (size_t)blockDim.x + t; i < total;
       i += (size_t)gridDim.x * blockDim.x) {
    int c = (int)(i & 127);
    float vv = bf2f(h[i]) * sc[c] + sh[c] + bf2f(x0b[i]);
    vv = relu_nanprop(vv);
    if (f) ((float*)out)[i] = vv;
    else   ((ushort_t*)out)[i] = f2bf(vv);
  }
}

extern "C" void kernel_launch(void* const* d_in, const int* in_sizes, int n_in,
                              void* d_out, int out_size, void* d_ws, size_t ws_size,
                              hipStream_t stream) {
  const void* x0  = d_in[0];
  const void* edges = d_in[1];
  const void* Wq1 = d_in[2];
  const void* Wk1 = d_in[3];
  const void* Wv1 = d_in[4];
  const void* Wr1 = d_in[5];
  const void* b1  = d_in[6];
  const void* gw1 = d_in[7];
  const void* bw1 = d_in[8];
  const void* Wq2 = d_in[9];
  const void* Wk2 = d_in[10];
  const void* Wv2 = d_in[11];
  const void* Wr2 = d_in[12];
  const void* b2  = d_in[13];
  const void* gw2 = d_in[14];
  const void* bw2 = d_in[15];

  int N = in_sizes[0] / 128;
  int E = in_sizes[1] / 2;
  int NCHUNK = (N + 255) / 256;
  int MT = (N + 127) / 128;

  uintptr_t base = (uintptr_t)d_ws;
  auto carve = [&](size_t bytes) -> void* {
    uintptr_t p = base;
    base += (bytes + 255) & ~(size_t)255;
    return (void*)p;
  };
  ushort_t* x0b = (ushort_t*)carve((size_t)N * 128 * 2);
  ushort_t* qtb = (ushort_t*)carve((size_t)N * 256 * 2);   // qt1 (128) / qt2 (256)
  ushort_t* aggb = (ushort_t*)carve((size_t)N * 256 * 2);  // agg output (128/256)
  ushort_t* hb = (ushort_t*)carve((size_t)N * 256 * 2);
  ushort_t* x1 = (ushort_t*)carve((size_t)N * 256 * 2);
  ushort_t* Wq1b = (ushort_t*)carve((size_t)128 * 256 * 2);
  ushort_t* Wk1b = (ushort_t*)carve((size_t)128 * 256 * 2);
  ushort_t* wcatB1 = (ushort_t*)carve((size_t)384 * 128 * 2);  // [M1^T | Wr1^T]
  ushort_t* wcatV1 = (ushort_t*)carve((size_t)256 * 128 * 2);  // Wv1^T
  ushort_t* Wq2b = (ushort_t*)carve((size_t)256 * 256 * 2);
  ushort_t* Wk2b = (ushort_t*)carve((size_t)256 * 256 * 2);
  ushort_t* wcatB2 = (ushort_t*)carve((size_t)384 * 256 * 2);  // [M2^T | Wr2^T]
  ushort_t* wcatV2 = (ushort_t*)carve((size_t)128 * 256 * 2);  // Wv2^T
  ushort_t* b1b  = (ushort_t*)carve(256 * 2);
  ushort_t* g1b  = (ushort_t*)carve(256 * 2);
  ushort_t* be1b = (ushort_t*)carve(256 * 2);
  ushort_t* b2b  = (ushort_t*)carve(128 * 2);
  ushort_t* g2b  = (ushort_t*)carve(128 * 2);
  ushort_t* be2b = (ushort_t*)carve(128 * 2);
  int* offs = (int*)carve((size_t)(N + 1) * 4);
  int* srcS = (int*)carve((size_t)E * 4);
  int* csum = (int*)carve(256 * 4);
  int* cpre = (int*)carve(256 * 4);
  // zeroed region: deg(N) fill(N) sums(1024 floats)
  int nzero = 2 * N + 1024;
  int* zreg2 = (int*)carve((size_t)nzero * 4);
  int* deg   = zreg2;
  int* fill  = zreg2 + N;
  float* sum1 = (float*)(zreg2 + 2 * N);
  float* sq1  = sum1 + 256;
  float* sum2 = sum1 + 512;
  float* sq2  = sum1 + 640;
  int* eflag = (int*)carve(256);   // [0]=edge wide, [1]=float32 flag (setup writes)
  int* fF = eflag + 1;

  size_t needed = base - (uintptr_t)d_ws;
  if (needed > ws_size) return;

  // 1: zero + dtype detects
  setup_kernel<<<258, 256, 0, stream>>>(zreg2, N, (const int*)edges, 2 * E, eflag,
                                        (const unsigned int*)x0, N * 128, fF);
  // 2: x0 cvt + params + weight prep + hist
  cvt_all_kernel<<<6145, 256, 0, stream>>>(x0, x0b, N * 128,
                                           b1, gw1, bw1, b2, gw2, bw2,
                                           b1b, g1b, be1b, b2b, g2b, be2b,
                                           Wq1, Wk1, Wv1, Wr1, Wq1b, Wk1b, wcatB1, wcatV1,
                                           Wq2, Wk2, Wv2, Wr2, Wq2b, Wk2b, wcatB2, wcatV2,
                                           edges, deg, E, N, eflag, fF);
  // 3-6: scan + scatter
  chunk_sum_kernel<<<NCHUNK, 256, 0, stream>>>(deg, csum, N);
  scan_small_kernel<<<1, 256, 0, stream>>>(csum, cpre, NCHUNK, offs, N);
  scan_final_kernel<<<NCHUNK, 256, 0, stream>>>(deg, cpre, offs, N);
  scatter_kernel<<<1024, 256, 0, stream>>>(edges, eflag, offs, fill, srcS, E, N);

  // M1^T = Wk1 @ Wq1^T -> wcatB1 rows 0..127;  M2^T = Wk2 @ Wq2^T -> wcatB2 rows 0..255
  gemm4_kernel<<<dim3(1, 1), 256, 0, stream>>>(Wk1b, Wq1b, wcatB1, wcatB1, wcatB1, wcatB1,
                                               b1b, 128, 256, 128, 128, 128, 128, 0);
  gemm4_kernel<<<dim3(2, 2), 256, 0, stream>>>(Wk2b, Wq2b, wcatB2, wcatB2, wcatB2, wcatB2,
                                               b1b, 256, 256, 256, 256, 256, 256, 0);

  int gAttn = (N + 3) / 4;        // one wave per node
  // Layer 1: [qt1 | h=x@Wr1+b1] = x0b @ wcatB1
  gemm4_kernel<<<dim3(MT, 3), 256, 0, stream>>>(x0b, wcatB1, qtb, qtb, qtb, hb, b1b,
                                                N, 128, 384, 128, 128, 128, 0);
  attn_kernel<<<gAttn, 256, 0, stream>>>(qtb, x0b, offs, srcS, aggb, 128, N);
  // h += agg @ Wv1
  gemm4_kernel<<<dim3(MT, 2), 256, 0, stream>>>(aggb, wcatV1, hb, hb, hb, hb, b1b,
                                                N, 128, 256, 256, 256, 256, 1);
  bn_stats_kernel<<<512, 256, 0, stream>>>(hb, sum1, sq1, N, 256);
  norm_relu_kernel<<<4096, 256, 0, stream>>>(hb, sum1, sq1, g1b, be1b, x1, N,
                                             (size_t)N * 256, 255);
  // Layer 2: [qt2 | h=x1@Wr2+b2] = x1 @ wcatB2
  gemm4_kernel<<<dim3(MT, 3), 256, 0, stream>>>(x1, wcatB2, qtb, qtb, qtb, hb, b2b,
                                                N, 256, 384, 256, 256, 256, 0);
  attn_kernel<<<gAttn, 256, 0, stream>>>(qtb, x1, offs, srcS, aggb, 256, N);
  // h += agg @ Wv2
  gemm4_kernel<<<dim3(MT, 1), 256, 0, stream>>>(aggb, wcatV2, hb, hb, hb, hb, b1b,
                                                N, 256, 128, 128, 128, 128, 1);
  bn_stats_kernel<<<512, 128, 0, stream>>>(hb, sum2, sq2, N, 128);
  final_kernel<<<4096, 256, 0, stream>>>(hb, sum2, sq2, g2b, be2b, x0b, d_out, fF, N,
                                         (size_t)N * 128);
}